// Round 3
// baseline (749.712 us; speedup 1.0000x reference)
//
#include <hip/hip_runtime.h>
#include <cstdint>
#include <cstddef>

#define NB 16
#define NC 84
#define NA 33600
#define NCLS 80
#define TOPK 1024
#define CANDCAP 4096
#define SCORE_THR 0.005f
#define IOU_THR 0.5f

// ---- 64-bit sort key: (monotonic fp32) << 32 | ~index ----------------------
// Larger key == (higher score, then lower index) == jax.lax.top_k order.
__device__ __forceinline__ unsigned mono_u32(float f) {
    unsigned u = __float_as_uint(f);
    return (u & 0x80000000u) ? ~u : (u | 0x80000000u);
}
__device__ __forceinline__ float key_val(uint64_t k) {
    unsigned u = (unsigned)(k >> 32);
    u = (u & 0x80000000u) ? (u & 0x7FFFFFFFu) : ~u;
    return __uint_as_float(u);
}
__device__ __forceinline__ int key_idx(uint64_t k) {
    return (int)(~(uint32_t)(k & 0xFFFFFFFFu));
}

// ---- Phase 1: per-anchor max/argmax over 80 classes + fused 64K-bin hist ---
__global__ __launch_bounds__(256) void score_hist_kernel(const float* __restrict__ x,
                                                         float* __restrict__ sval,
                                                         int* __restrict__ cid,
                                                         unsigned* __restrict__ hist) {
    int gid = blockIdx.x * 256 + threadIdx.x;
    if (gid >= NB * NA) return;
    int b = gid / NA;
    int a = gid - b * NA;
    const float* p = x + (size_t)b * NC * NA + (size_t)4 * NA + a;
    float best = p[0];
    int bc = 0;
#pragma unroll 8
    for (int c = 1; c < NCLS; ++c) {
        float v = p[(size_t)c * NA];
        if (v > best) { best = v; bc = c; }   // strict > == first-occurrence argmax
    }
    float s = (best > SCORE_THR) ? best : -INFINITY;
    sval[gid] = s;
    cid[gid] = bc;
    unsigned bin = mono_u32(s) >> 16;
    atomicAdd(&hist[((unsigned)b << 16) + bin], 1u);
}

// ---- Phase 2a: find per-batch cut bin (1024th largest) ---------------------
__global__ __launch_bounds__(256) void scan_kernel(const unsigned* __restrict__ hist,
                                                   unsigned* __restrict__ cutbin) {
    int b = blockIdx.x;
    int t = threadIdx.x;
    __shared__ unsigned csum[256];
    const unsigned* h = hist + ((unsigned)b << 16);
    unsigned local = 0;
#pragma unroll 8
    for (int q = 0; q < 256; ++q)
        local += h[65535 - (t * 256 + q)];
    csum[t] = local;
    __syncthreads();
    for (int off = 1; off < 256; off <<= 1) {
        unsigned v = (t >= off) ? csum[t - off] : 0u;
        __syncthreads();
        csum[t] += v;
        __syncthreads();
    }
    unsigned incl = csum[t], excl = incl - local;
    if (excl < TOPK && incl >= TOPK) {
        unsigned cum = excl;
        for (int q = 0; q < 256; ++q) {
            unsigned bin = 65535 - (t * 256 + q);
            unsigned c = h[bin];
            if (cum + c >= TOPK) { cutbin[b] = bin; break; }
            cum += c;
        }
    }
}

// ---- Phase 2b: compact candidates (bin >= cutbin), unordered ---------------
__global__ __launch_bounds__(256) void compact_kernel(const float* __restrict__ sval,
                                                      const unsigned* __restrict__ cutbin,
                                                      uint64_t* __restrict__ cand,
                                                      unsigned* __restrict__ cnt) {
    int gid = blockIdx.x * 256 + threadIdx.x;
    if (gid >= NB * NA) return;
    int b = gid / NA;
    int a = gid - b * NA;
    unsigned u = mono_u32(sval[gid]);
    if ((u >> 16) >= cutbin[b]) {
        unsigned pos = atomicAdd(&cnt[b], 1u);
        if (pos < CANDCAP)
            cand[((unsigned)b << 12) + pos] = ((uint64_t)u << 32) | (uint32_t)(~(uint32_t)a);
    }
}

// ---- Phase 2c: bitonic sort candidates, emit exact sorted top-1024 ---------
__global__ __launch_bounds__(256) void sortk_kernel(const uint64_t* __restrict__ cand,
                                                    const unsigned* __restrict__ cnt,
                                                    float* __restrict__ topval,
                                                    int* __restrict__ topidx) {
    int b = blockIdx.x;
    int t = threadIdx.x;
    __shared__ uint64_t lk[CANDCAP];
    unsigned C = cnt[b];
    if (C > CANDCAP) C = CANDCAP;
    for (int i = t; i < CANDCAP; i += 256)
        lk[i] = (i < (int)C) ? cand[((unsigned)b << 12) + i] : 0ULL;
    __syncthreads();
    for (int k = 2; k <= CANDCAP; k <<= 1) {
        for (int j = k >> 1; j > 0; j >>= 1) {
            for (int i = t; i < CANDCAP; i += 256) {
                int ixj = i ^ j;
                if (ixj > i) {
                    uint64_t A = lk[i], B = lk[ixj];
                    bool up = ((i & k) == 0);
                    if (up ? (A < B) : (A > B)) { lk[i] = B; lk[ixj] = A; }
                }
            }
            __syncthreads();
        }
    }
    for (int i = t; i < TOPK; i += 256) {
        uint64_t key = lk[i];
        topval[b * TOPK + i] = key_val(key);
        topidx[b * TOPK + i] = key_idx(key);
    }
}

// ---- Phase 3a: gather top-1024 boxes SoA + class ids -----------------------
__global__ __launch_bounds__(256) void boxes_kernel(const float* __restrict__ x,
                                                    const int* __restrict__ cid,
                                                    const int* __restrict__ tidx,
                                                    float* __restrict__ bx1, float* __restrict__ by1,
                                                    float* __restrict__ bx2, float* __restrict__ by2,
                                                    float* __restrict__ bar, int* __restrict__ tcid) {
    int b = blockIdx.x;
    int base = b << 10;
    const float* xb = x + (size_t)b * NC * NA;
    for (int k = threadIdx.x; k < TOPK; k += 256) {
        int idx = tidx[base + k];
        float x1 = xb[idx], y1 = xb[NA + idx], x2 = xb[2 * NA + idx], y2 = xb[3 * NA + idx];
        bx1[base + k] = x1; by1[base + k] = y1;
        bx2[base + k] = x2; by2[base + k] = y2;
        bar[base + k] = (x2 - x1) * (y2 - y1);
        tcid[base + k] = cid[b * NA + idx];
    }
}

// ---- Phase 3b: parallel suppression bit-matrix -----------------------------
#define LDSPAD(j) ((j) + ((j) >> 6))
__global__ __launch_bounds__(256) void maskbuild_kernel(const float* __restrict__ bx1,
                                                        const float* __restrict__ by1,
                                                        const float* __restrict__ bx2,
                                                        const float* __restrict__ by2,
                                                        const float* __restrict__ bar,
                                                        const float* __restrict__ tval,
                                                        uint64_t* __restrict__ M,
                                                        int* __restrict__ rowflag) {
    int b = blockIdx.x >> 6;
    int r0 = (blockIdx.x & 63) << 4;
    int t = threadIdx.x;
    int r = r0 + (t >> 4);
    int w = t & 15;
    int base = b << 10;
    __shared__ float sx1[TOPK + 16], sy1[TOPK + 16], sx2[TOPK + 16], sy2[TOPK + 16], sar[TOPK + 16];
    __shared__ int anyf[256];

    for (int j = t; j < TOPK; j += 256) {
        int ji = LDSPAD(j);
        sx1[ji] = bx1[base + j]; sy1[ji] = by1[base + j];
        sx2[ji] = bx2[base + j]; sy2[ji] = by2[base + j];
        sar[ji] = bar[base + j];
    }
    __syncthreads();

    int ri = LDSPAD(r);
    float ix1 = sx1[ri], iy1 = sy1[ri], ix2 = sx2[ri], iy2 = sy2[ri], ia = sar[ri];
    uint64_t m = 0;
#pragma unroll 8
    for (int jj = 0; jj < 64; ++jj) {
        int j = (w << 6) + jj;
        int ji = w * 65 + jj;
        float ltx = fmaxf(ix1, sx1[ji]);
        float lty = fmaxf(iy1, sy1[ji]);
        float rbx = fminf(ix2, sx2[ji]);
        float rby = fminf(iy2, sy2[ji]);
        float ww = fmaxf(rbx - ltx, 0.0f);
        float hh = fmaxf(rby - lty, 0.0f);
        float inter = ww * hh;
        float uni = ia + sar[ji] - inter;      // same op order as reference
        float iou = inter / fmaxf(uni, 1e-9f);
        if (j > r && iou > IOU_THR) m |= (1ULL << jj);
    }
    M[((size_t)(base + r) << 4) + w] = m;
    anyf[t] = (m != 0ULL);
    __syncthreads();
    if (w == 0) {
        int any = 0;
#pragma unroll
        for (int q = 0; q < 16; ++q) any |= anyf[t + q];
        bool valid = tval[base + r] > SCORE_THR;
        rowflag[base + r] = (any && valid) ? 1 : 0;
    }
}

// ---- Phase 3c: serial greedy sweep, register-staged rows + epilogue --------
// One wave/batch. Lane l = 16g+w. remv authoritative in lanes 0..15 (word w).
// Rows chunked by 64: each lane preloads 16 rows' words (independent global
// loads, one waitcnt), so the serial chain is shfl->or only (~40 cyc/row).
__global__ __launch_bounds__(64) void sweep_kernel(const uint64_t* __restrict__ M,
                                                   const int* __restrict__ rowflag,
                                                   const float* __restrict__ tval,
                                                   const int* __restrict__ tcid,
                                                   const float* __restrict__ bx1,
                                                   const float* __restrict__ by1,
                                                   const float* __restrict__ bx2,
                                                   const float* __restrict__ by2,
                                                   float* __restrict__ out) {
    int b = blockIdx.x;
    int l = threadIdx.x;
    int base = b << 10;
    int w = l & 15, g = l >> 4;
    __shared__ int list[TOPK];

    float tv[16];
#pragma unroll
    for (int s = 0; s < 16; ++s) tv[s] = tval[base + (s << 6) + l];

    uint64_t vword = 0;
#pragma unroll
    for (int s = 0; s < 16; ++s) {
        uint64_t bal = __ballot(tv[s] > SCORE_THR);
        if (l == s) vword = bal;
    }

    int cnt = 0;
#pragma unroll
    for (int s = 0; s < 16; ++s) {
        int flag = rowflag[base + (s << 6) + l];
        uint64_t m = __ballot(flag != 0);
        if (flag) {
            int pos = cnt + __popcll(m & ((1ULL << l) - 1ULL));
            list[pos] = (s << 6) + l;
        }
        cnt += __popcll(m);
    }
    __syncthreads();

    uint64_t remv = 0;
    for (int chunk = 0; chunk < cnt; chunk += 64) {
        int m = min(64, cnt - chunk);
        int idx_l = chunk + l;
        int myi = list[(idx_l < cnt) ? idx_l : 0];   // lane l holds list[chunk+l]
        uint64_t rows[16];
#pragma unroll
        for (int q = 0; q < 16; ++q) {
            int it = chunk + q * 4 + g;              // lane group g loads row it, word w
            int it2 = (it < cnt) ? it : 0;
            uint64_t v = M[((size_t)(base + list[it2]) << 4) + w];
            rows[q] = (it < cnt) ? v : 0ULL;
        }
        for (int r = 0; r < m; ++r) {
            int i = __shfl(myi, r, 64);
            uint64_t row = __shfl(rows[r >> 2], ((r & 3) << 4) + w, 64);
            uint64_t rb = __shfl(remv, i >> 6, 64);
            bool kept = !((rb >> (i & 63)) & 1ULL);
            remv |= (kept && l < 16) ? row : 0ULL;
        }
    }

    uint64_t kf = vword & ~remv;   // lane s holds keep word for group s
#pragma unroll
    for (int s = 0; s < 16; ++s) {
        uint64_t kw = __shfl(kf, s, 64);
        bool kp = (kw >> l) & 1ULL;
        int k = (s << 6) + l;
        float x1 = bx1[base + k], y1 = by1[base + k];
        float x2 = bx2[base + k], y2 = by2[base + k];
        float* po = out + ((size_t)(base + k)) * 6;
        po[0] = kp ? x1 : 0.0f;
        po[1] = kp ? y1 : 0.0f;
        po[2] = kp ? x2 : 0.0f;
        po[3] = kp ? y2 : 0.0f;
        po[4] = kp ? tv[s] : 0.0f;
        po[5] = kp ? (float)tcid[base + k] : 0.0f;
        out[(size_t)NB * TOPK * 6 + base + k] = kp ? 1.0f : 0.0f;
    }
}

extern "C" void kernel_launch(void* const* d_in, const int* in_sizes, int n_in,
                              void* d_out, int out_size, void* d_ws, size_t ws_size,
                              hipStream_t stream) {
    const float* x = (const float*)d_in[0];
    float* out = (float*)d_out;
    char* ws = (char*)d_ws;

    size_t off = 0;
    auto alloc = [&](size_t bytes) { void* p = ws + off; off = (off + bytes + 255) & ~(size_t)255; return p; };
    float*    sval    = (float*)alloc((size_t)NB * NA * 4);
    int*      cid     = (int*)alloc((size_t)NB * NA * 4);
    unsigned* hist    = (unsigned*)alloc((size_t)NB * 65536 * 4);   // reused as M after scan
    unsigned* cutbin  = (unsigned*)alloc(NB * 4);
    unsigned* cnt     = (unsigned*)alloc(NB * 4);
    uint64_t* cand    = (uint64_t*)alloc((size_t)NB * CANDCAP * 8);
    float*    tval    = (float*)alloc((size_t)NB * TOPK * 4);
    int*      tidx    = (int*)alloc((size_t)NB * TOPK * 4);
    float*    bx1     = (float*)alloc((size_t)NB * TOPK * 4);
    float*    by1     = (float*)alloc((size_t)NB * TOPK * 4);
    float*    bx2     = (float*)alloc((size_t)NB * TOPK * 4);
    float*    by2     = (float*)alloc((size_t)NB * TOPK * 4);
    float*    bar     = (float*)alloc((size_t)NB * TOPK * 4);
    int*      tcid    = (int*)alloc((size_t)NB * TOPK * 4);
    int*      rowflag = (int*)alloc((size_t)NB * TOPK * 4);
    uint64_t* M       = (uint64_t*)hist;   // alias: hist dead after scan_kernel

    hipMemsetAsync(hist, 0, (size_t)NB * 65536 * 4, stream);
    hipMemsetAsync(cnt, 0, NB * 4, stream);

    int total = NB * NA;
    score_hist_kernel<<<(total + 255) / 256, 256, 0, stream>>>(x, sval, cid, hist);
    scan_kernel<<<NB, 256, 0, stream>>>(hist, cutbin);
    compact_kernel<<<(total + 255) / 256, 256, 0, stream>>>(sval, cutbin, cand, cnt);
    sortk_kernel<<<NB, 256, 0, stream>>>(cand, cnt, tval, tidx);
    boxes_kernel<<<NB, 256, 0, stream>>>(x, cid, tidx, bx1, by1, bx2, by2, bar, tcid);
    maskbuild_kernel<<<NB * 64, 256, 0, stream>>>(bx1, by1, bx2, by2, bar, tval, M, rowflag);
    sweep_kernel<<<NB, 64, 0, stream>>>(M, rowflag, tval, tcid, bx1, by1, bx2, by2, out);
}

// Round 4
// 412.491 us; speedup vs baseline: 1.8175x; 1.8175x over previous
//
#include <hip/hip_runtime.h>
#include <cstdint>
#include <cstddef>

#define NB 16
#define NC 84
#define NA 33600
#define NCLS 80
#define TOPK 1024
#define NBIN 8192        // coarse bins: mono_u32 >> 19 (sign+exp+4 mantissa bits)
#define CANDCAP 8192
#define SELCAP 2048
#define SCORE_THR 0.005f
#define IOU_THR 0.5f

// ---- 64-bit sort key: (monotonic fp32) << 32 | ~index ----------------------
// Larger key == (higher score, then lower index) == jax.lax.top_k order.
__device__ __forceinline__ unsigned mono_u32(float f) {
    unsigned u = __float_as_uint(f);
    return (u & 0x80000000u) ? ~u : (u | 0x80000000u);
}
__device__ __forceinline__ float key_val(uint64_t k) {
    unsigned u = (unsigned)(k >> 32);
    u = (u & 0x80000000u) ? (u & 0x7FFFFFFFu) : ~u;
    return __uint_as_float(u);
}
__device__ __forceinline__ int key_idx(uint64_t k) {
    return (int)(~(uint32_t)(k & 0xFFFFFFFFu));
}

// ---- Phase 1: per-anchor max/argmax over 80 classes (float4, 4 anchors/thr) -
__global__ __launch_bounds__(256) void score_kernel(const float* __restrict__ x,
                                                    float* __restrict__ sval,
                                                    int* __restrict__ cid) {
    int gid = blockIdx.x * 256 + threadIdx.x;     // NB*NA/4 threads
    if (gid >= NB * (NA / 4)) return;
    int b = gid / (NA / 4);
    int q = gid - b * (NA / 4);
    const float4* p = (const float4*)(x + (size_t)b * NC * NA + (size_t)4 * NA) + q;
    float4 best = p[0];
    int4 bc = {0, 0, 0, 0};
#pragma unroll 4
    for (int c = 1; c < NCLS; ++c) {
        float4 v = p[(size_t)c * (NA / 4)];
        if (v.x > best.x) { best.x = v.x; bc.x = c; }
        if (v.y > best.y) { best.y = v.y; bc.y = c; }
        if (v.z > best.z) { best.z = v.z; bc.z = c; }
        if (v.w > best.w) { best.w = v.w; bc.w = c; }
    }
    float4 s;
    s.x = (best.x > SCORE_THR) ? best.x : -INFINITY;
    s.y = (best.y > SCORE_THR) ? best.y : -INFINITY;
    s.z = (best.z > SCORE_THR) ? best.z : -INFINITY;
    s.w = (best.w > SCORE_THR) ? best.w : -INFINITY;
    ((float4*)sval)[gid] = s;
    ((int4*)cid)[gid] = bc;
}

// ---- Phase 2a: LDS-privatized 8192-bin histogram (16 blocks per batch) -----
__global__ __launch_bounds__(256) void hist_kernel(const float* __restrict__ sval,
                                                   unsigned* __restrict__ hist) {
    int b = blockIdx.x >> 4;
    int sub = blockIdx.x & 15;
    int t = threadIdx.x;
    __shared__ unsigned h[NBIN];
    for (int i = t; i < NBIN; i += 256) h[i] = 0;
    __syncthreads();
    int a0 = sub * (NA / 16), a1 = a0 + (NA / 16);   // NA/16 = 2100
    const float* sv = sval + (size_t)b * NA;
    for (int a = a0 + t; a < a1; a += 256)
        atomicAdd(&h[mono_u32(sv[a]) >> 19], 1u);
    __syncthreads();
    for (int i = t; i < NBIN; i += 256)
        if (h[i]) atomicAdd(&hist[b * NBIN + i], h[i]);
}

// ---- Phase 2b: per-batch cut bin (bin containing the 1024th-largest) -------
__global__ __launch_bounds__(256) void scan_kernel(const unsigned* __restrict__ hist,
                                                   unsigned* __restrict__ cutbin) {
    int b = blockIdx.x;
    int t = threadIdx.x;
    __shared__ unsigned csum[256];
    const unsigned* h = hist + b * NBIN;
    unsigned local = 0;
#pragma unroll 8
    for (int q = 0; q < 32; ++q) local += h[NBIN - 1 - (t * 32 + q)];
    csum[t] = local;
    __syncthreads();
    for (int off = 1; off < 256; off <<= 1) {
        unsigned v = (t >= off) ? csum[t - off] : 0u;
        __syncthreads();
        csum[t] += v;
        __syncthreads();
    }
    unsigned incl = csum[t], excl = incl - local;
    if (excl < TOPK && incl >= TOPK) {
        unsigned cum = excl;
        for (int q = 0; q < 32; ++q) {
            unsigned bin = NBIN - 1 - (t * 32 + q);
            unsigned c = h[bin];
            if (cum + c >= TOPK) { cutbin[b] = bin; break; }
            cum += c;
        }
    }
}

// ---- Phase 2c: compact candidates, LDS-staged (1 global atomic/blk/seg) ----
__global__ __launch_bounds__(256) void compact_kernel(const float* __restrict__ sval,
                                                      const unsigned* __restrict__ cutbin,
                                                      uint64_t* __restrict__ cand,
                                                      unsigned* __restrict__ cnt) {
    int gid = blockIdx.x * 256 + threadIdx.x;
    int b = gid / NA;
    int a = gid - b * NA;
    int b_first = (blockIdx.x * 256) / NA;   // block spans <=2 batches
    int seg = b - b_first;
    __shared__ unsigned lcnt[2], lbase[2];
    __shared__ uint64_t k0[256], k1[256];
    if (threadIdx.x < 2) lcnt[threadIdx.x] = 0;
    __syncthreads();
    unsigned u = mono_u32(sval[gid]);
    if ((u >> 19) >= cutbin[b]) {
        unsigned pos = atomicAdd(&lcnt[seg], 1u);
        uint64_t key = ((uint64_t)u << 32) | (uint32_t)(~(uint32_t)a);
        if (seg) k1[pos] = key; else k0[pos] = key;
    }
    __syncthreads();
    if (threadIdx.x == 0 && lcnt[0]) lbase[0] = atomicAdd(&cnt[b_first * 64], lcnt[0]);
    if (threadIdx.x == 1 && lcnt[1]) lbase[1] = atomicAdd(&cnt[(b_first + 1) * 64], lcnt[1]);
    __syncthreads();
    if (threadIdx.x < lcnt[0]) {
        unsigned p = lbase[0] + threadIdx.x;
        if (p < CANDCAP) cand[((size_t)b_first << 13) + p] = k0[threadIdx.x];
    }
    if (threadIdx.x < lcnt[1]) {
        unsigned p = lbase[1] + threadIdx.x;
        if (p < CANDCAP) cand[((size_t)(b_first + 1) << 13) + p] = k1[threadIdx.x];
    }
}

// ---- Phase 2d: sub-select to ~1030, bitonic sort 2048, emit top-1024 -------
__device__ __forceinline__ void bitonic_desc(uint64_t* A, int n, int tid) {
    for (int k = 2; k <= n; k <<= 1) {
        for (int j = k >> 1; j > 0; j >>= 1) {
            for (int i = tid; i < n; i += 256) {
                int ixj = i ^ j;
                if (ixj > i) {
                    uint64_t a = A[i], b2 = A[ixj];
                    bool up = ((i & k) == 0);
                    if (up ? (a < b2) : (a > b2)) { A[i] = b2; A[ixj] = a; }
                }
            }
            __syncthreads();
        }
    }
}

__global__ __launch_bounds__(256) void sortk_kernel(const uint64_t* __restrict__ cand,
                                                    const unsigned* __restrict__ cnt,
                                                    const unsigned* __restrict__ cutbin,
                                                    float* __restrict__ topval,
                                                    int* __restrict__ topidx) {
    int b = blockIdx.x;
    int t = threadIdx.x;
    __shared__ uint64_t lk[CANDCAP];     // 64 KB
    __shared__ uint64_t lsel[SELCAP];    // 16 KB
    __shared__ unsigned sh[256];
    __shared__ unsigned snA, snSel, ssubcut;
    unsigned C = cnt[b * 64];
    if (C > CANDCAP) C = CANDCAP;
    unsigned cb = cutbin[b];

    for (int i = t; i < CANDCAP; i += 256)
        lk[i] = (i < (int)C) ? cand[((size_t)b << 13) + i] : 0ULL;
    for (int i = t; i < SELCAP; i += 256) lsel[i] = 0ULL;
    for (int i = t; i < 256; i += 256) sh[i] = 0;
    if (t == 0) { snA = 0; snSel = 0; }
    __syncthreads();

    // count strictly-above-bin candidates; sub-histogram of cut-bin candidates
    unsigned myA = 0;
    for (int i = t; i < (int)C; i += 256) {
        unsigned u = (unsigned)(lk[i] >> 32);
        if ((u >> 19) > cb) myA++;
        else atomicAdd(&sh[(u >> 11) & 255u], 1u);
    }
    atomicAdd(&snA, myA);
    __syncthreads();

    if (t == 0) {
        unsigned r = TOPK - snA;       // >=1 by cut-bin construction
        unsigned cum = 0, sc = 0;
        for (int s = 255; s >= 0; --s) {
            cum += sh[s];
            if (cum >= r) { sc = (unsigned)s; break; }
        }
        ssubcut = sc;
    }
    __syncthreads();
    unsigned subcut = ssubcut;

    // wave-aggregated compaction of selected keys into lsel
    int lane = t & 63;
    for (int i = t; i < CANDCAP; i += 256) {
        unsigned u = (unsigned)(lk[i] >> 32);
        unsigned bin = u >> 19;
        bool sel = (bin > cb) || (bin == cb && ((u >> 11) & 255u) >= subcut);
        uint64_t mask = __ballot(sel);
        if (mask) {
            int ldr = __ffsll((unsigned long long)mask) - 1;
            unsigned base = 0;
            if (lane == ldr) base = atomicAdd(&snSel, (unsigned)__popcll(mask));
            base = __shfl(base, ldr, 64);
            if (sel) {
                unsigned p = base + (unsigned)__popcll(mask & ((1ULL << lane) - 1ULL));
                if (p < SELCAP) lsel[p] = lk[i];
            }
        }
    }
    __syncthreads();
    unsigned nSel = snSel;

    // sort (fallback to full sort if selection overflowed — exactness kept)
    uint64_t* buf;
    if (nSel <= SELCAP) { bitonic_desc(lsel, SELCAP, t); buf = lsel; }
    else                { bitonic_desc(lk, CANDCAP, t);  buf = lk;  }

    for (int i = t; i < TOPK; i += 256) {
        uint64_t key = buf[i];
        topval[b * TOPK + i] = key_val(key);
        topidx[b * TOPK + i] = key_idx(key);
    }
}

// ---- Phase 3a: gather top-1024 boxes SoA + class ids -----------------------
__global__ __launch_bounds__(256) void boxes_kernel(const float* __restrict__ x,
                                                    const int* __restrict__ cid,
                                                    const int* __restrict__ tidx,
                                                    float* __restrict__ bx1, float* __restrict__ by1,
                                                    float* __restrict__ bx2, float* __restrict__ by2,
                                                    float* __restrict__ bar, int* __restrict__ tcid) {
    int b = blockIdx.x;
    int base = b << 10;
    const float* xb = x + (size_t)b * NC * NA;
    for (int k = threadIdx.x; k < TOPK; k += 256) {
        int idx = tidx[base + k];
        float x1 = xb[idx], y1 = xb[NA + idx], x2 = xb[2 * NA + idx], y2 = xb[3 * NA + idx];
        bx1[base + k] = x1; by1[base + k] = y1;
        bx2[base + k] = x2; by2[base + k] = y2;
        bar[base + k] = (x2 - x1) * (y2 - y1);
        tcid[base + k] = cid[b * NA + idx];
    }
}

// ---- Phase 3b: parallel suppression bit-matrix -----------------------------
#define LDSPAD(j) ((j) + ((j) >> 6))
__global__ __launch_bounds__(256) void maskbuild_kernel(const float* __restrict__ bx1,
                                                        const float* __restrict__ by1,
                                                        const float* __restrict__ bx2,
                                                        const float* __restrict__ by2,
                                                        const float* __restrict__ bar,
                                                        const float* __restrict__ tval,
                                                        uint64_t* __restrict__ M,
                                                        int* __restrict__ rowflag) {
    int b = blockIdx.x >> 6;
    int r0 = (blockIdx.x & 63) << 4;
    int t = threadIdx.x;
    int r = r0 + (t >> 4);
    int w = t & 15;
    int base = b << 10;
    __shared__ float sx1[TOPK + 16], sy1[TOPK + 16], sx2[TOPK + 16], sy2[TOPK + 16], sar[TOPK + 16];
    __shared__ int anyf[256];

    for (int j = t; j < TOPK; j += 256) {
        int ji = LDSPAD(j);
        sx1[ji] = bx1[base + j]; sy1[ji] = by1[base + j];
        sx2[ji] = bx2[base + j]; sy2[ji] = by2[base + j];
        sar[ji] = bar[base + j];
    }
    __syncthreads();

    int ri = LDSPAD(r);
    float ix1 = sx1[ri], iy1 = sy1[ri], ix2 = sx2[ri], iy2 = sy2[ri], ia = sar[ri];
    uint64_t m = 0;
#pragma unroll 8
    for (int jj = 0; jj < 64; ++jj) {
        int j = (w << 6) + jj;
        int ji = w * 65 + jj;
        float ltx = fmaxf(ix1, sx1[ji]);
        float lty = fmaxf(iy1, sy1[ji]);
        float rbx = fminf(ix2, sx2[ji]);
        float rby = fminf(iy2, sy2[ji]);
        float ww = fmaxf(rbx - ltx, 0.0f);
        float hh = fmaxf(rby - lty, 0.0f);
        float inter = ww * hh;
        float uni = ia + sar[ji] - inter;      // same op order as reference
        float iou = inter / fmaxf(uni, 1e-9f);
        if (j > r && iou > IOU_THR) m |= (1ULL << jj);
    }
    M[((size_t)(base + r) << 4) + w] = m;
    anyf[t] = (m != 0ULL);
    __syncthreads();
    if (w == 0) {
        int any = 0;
#pragma unroll
        for (int q = 0; q < 16; ++q) any |= anyf[t + q];
        bool valid = tval[base + r] > SCORE_THR;
        rowflag[base + r] = (any && valid) ? 1 : 0;
    }
}

// ---- Phase 3c: serial greedy sweep, register-staged rows + epilogue --------
__global__ __launch_bounds__(64) void sweep_kernel(const uint64_t* __restrict__ M,
                                                   const int* __restrict__ rowflag,
                                                   const float* __restrict__ tval,
                                                   const int* __restrict__ tcid,
                                                   const float* __restrict__ bx1,
                                                   const float* __restrict__ by1,
                                                   const float* __restrict__ bx2,
                                                   const float* __restrict__ by2,
                                                   float* __restrict__ out) {
    int b = blockIdx.x;
    int l = threadIdx.x;
    int base = b << 10;
    int w = l & 15, g = l >> 4;
    __shared__ int list[TOPK];

    float tv[16];
#pragma unroll
    for (int s = 0; s < 16; ++s) tv[s] = tval[base + (s << 6) + l];

    uint64_t vword = 0;
#pragma unroll
    for (int s = 0; s < 16; ++s) {
        uint64_t bal = __ballot(tv[s] > SCORE_THR);
        if (l == s) vword = bal;
    }

    int cnt = 0;
#pragma unroll
    for (int s = 0; s < 16; ++s) {
        int flag = rowflag[base + (s << 6) + l];
        uint64_t m = __ballot(flag != 0);
        if (flag) {
            int pos = cnt + __popcll(m & ((1ULL << l) - 1ULL));
            list[pos] = (s << 6) + l;
        }
        cnt += __popcll(m);
    }
    __syncthreads();

    uint64_t remv = 0;
    for (int chunk = 0; chunk < cnt; chunk += 64) {
        int m = min(64, cnt - chunk);
        int idx_l = chunk + l;
        int myi = list[(idx_l < cnt) ? idx_l : 0];
        uint64_t rows[16];
#pragma unroll
        for (int q = 0; q < 16; ++q) {
            int it = chunk + q * 4 + g;
            int it2 = (it < cnt) ? it : 0;
            uint64_t v = M[((size_t)(base + list[it2]) << 4) + w];
            rows[q] = (it < cnt) ? v : 0ULL;
        }
        for (int r = 0; r < m; ++r) {
            int i = __shfl(myi, r, 64);
            uint64_t row = __shfl(rows[r >> 2], ((r & 3) << 4) + w, 64);
            uint64_t rb = __shfl(remv, i >> 6, 64);
            bool kept = !((rb >> (i & 63)) & 1ULL);
            remv |= (kept && l < 16) ? row : 0ULL;
        }
    }

    uint64_t kf = vword & ~remv;
#pragma unroll
    for (int s = 0; s < 16; ++s) {
        uint64_t kw = __shfl(kf, s, 64);
        bool kp = (kw >> l) & 1ULL;
        int k = (s << 6) + l;
        float x1 = bx1[base + k], y1 = by1[base + k];
        float x2 = bx2[base + k], y2 = by2[base + k];
        float* po = out + ((size_t)(base + k)) * 6;
        po[0] = kp ? x1 : 0.0f;
        po[1] = kp ? y1 : 0.0f;
        po[2] = kp ? x2 : 0.0f;
        po[3] = kp ? y2 : 0.0f;
        po[4] = kp ? tv[s] : 0.0f;
        po[5] = kp ? (float)tcid[base + k] : 0.0f;
        out[(size_t)NB * TOPK * 6 + base + k] = kp ? 1.0f : 0.0f;
    }
}

extern "C" void kernel_launch(void* const* d_in, const int* in_sizes, int n_in,
                              void* d_out, int out_size, void* d_ws, size_t ws_size,
                              hipStream_t stream) {
    const float* x = (const float*)d_in[0];
    float* out = (float*)d_out;
    char* ws = (char*)d_ws;

    size_t off = 0;
    auto alloc = [&](size_t bytes) { void* p = ws + off; off = (off + bytes + 255) & ~(size_t)255; return p; };
    float*    sval    = (float*)alloc((size_t)NB * NA * 4);
    int*      cid     = (int*)alloc((size_t)NB * NA * 4);
    unsigned* hist    = (unsigned*)alloc((size_t)NB * NBIN * 4);
    unsigned* cutbin  = (unsigned*)alloc(NB * 4);
    unsigned* cnt     = (unsigned*)alloc((size_t)NB * 64 * 4);   // 256B stride/batch
    uint64_t* cand    = (uint64_t*)alloc((size_t)NB * CANDCAP * 8);
    float*    tval    = (float*)alloc((size_t)NB * TOPK * 4);
    int*      tidx    = (int*)alloc((size_t)NB * TOPK * 4);
    float*    bx1     = (float*)alloc((size_t)NB * TOPK * 4);
    float*    by1     = (float*)alloc((size_t)NB * TOPK * 4);
    float*    bx2     = (float*)alloc((size_t)NB * TOPK * 4);
    float*    by2     = (float*)alloc((size_t)NB * TOPK * 4);
    float*    bar     = (float*)alloc((size_t)NB * TOPK * 4);
    int*      tcid    = (int*)alloc((size_t)NB * TOPK * 4);
    int*      rowflag = (int*)alloc((size_t)NB * TOPK * 4);
    uint64_t* M       = (uint64_t*)alloc((size_t)NB * TOPK * 16 * 8);

    hipMemsetAsync(hist, 0, (size_t)NB * NBIN * 4, stream);
    hipMemsetAsync(cnt, 0, (size_t)NB * 64 * 4, stream);

    score_kernel<<<NB * (NA / 4) / 256, 256, 0, stream>>>(x, sval, cid);
    hist_kernel<<<NB * 16, 256, 0, stream>>>(sval, hist);
    scan_kernel<<<NB, 256, 0, stream>>>(hist, cutbin);
    compact_kernel<<<NB * NA / 256, 256, 0, stream>>>(sval, cutbin, cand, cnt);
    sortk_kernel<<<NB, 256, 0, stream>>>(cand, cnt, cutbin, tval, tidx);
    boxes_kernel<<<NB, 256, 0, stream>>>(x, cid, tidx, bx1, by1, bx2, by2, bar, tcid);
    maskbuild_kernel<<<NB * 64, 256, 0, stream>>>(bx1, by1, bx2, by2, bar, tval, M, rowflag);
    sweep_kernel<<<NB, 64, 0, stream>>>(M, rowflag, tval, tcid, bx1, by1, bx2, by2, out);
}